// Round 12
// baseline (30.853 us; speedup 1.0000x reference)
//
#include <hip/hip_runtime.h>
#include <math.h>

#define IMG  1024
#define ROWS 32     // 32 x 16 = 512 blocks -> 2 resident blocks/CU (LDS-bound)

#define NEG4 make_float4(-INFINITY, -INFINITY, -INFINITY, -INFINITY)

__device__ __forceinline__ float4 max4(const float4 a, const float4 b) {
    return make_float4(fmaxf(a.x, b.x), fmaxf(a.y, b.y),
                       fmaxf(a.z, b.z), fmaxf(a.w, b.w));
}

// sliding 9-wide max: 4 outputs from 12 inputs (v0=a0..3, v1=a4..7, v2=a8..11)
__device__ __forceinline__ float4 hmax9(const float4 v0, const float4 v1, const float4 v2) {
    const float core = fmaxf(fmaxf(fmaxf(v0.w, v1.x), fmaxf(v1.y, v1.z)),
                             fmaxf(v1.w, v2.x));                     // a3..a8
    const float p12  = fmaxf(v0.y, v0.z);
    const float q910 = fmaxf(v2.y, v2.z);
    float4 r;
    r.x = fmaxf(core, fmaxf(v0.x, p12));        // a0..a8
    r.y = fmaxf(core, fmaxf(p12, v2.y));        // a1..a9
    r.z = fmaxf(core, fmaxf(v0.z, q910));       // a2..a10
    r.w = fmaxf(core, fmaxf(q910, v2.w));       // a3..a11
    return r;
}

__global__ __launch_bounds__(256, 1)
void dilate9x9(const float* __restrict__ in, float* __restrict__ out) {
    // ring[slot][r] = one full 4 KB image row staged by DMA (all 4 waves, 1 KB each)
    __shared__ float ring[2][8][IMG];            // 64 KB

    const int tid = threadIdx.x;
    const int w   = tid >> 6;                    // wave 0..3 (cols 256w .. 256w+255)
    const int ln  = tid & 63;
    const int x4  = tid << 2;                    // thread's 4 output cols
    const int y0  = blockIdx.x * ROWS;
    const int b   = blockIdx.y;

    const float* img  = in  + (size_t)b * IMG * IMG;
    float*       oimg = out + (size_t)b * IMG * IMG;

    // one DMA: this wave stages its 1 KB quarter of image row cy into ring[slot][r]
    auto stage = [&](const int slot, const int r, const int cy) {
        const float* gsrc = img + (size_t)cy * IMG + (w << 8) + (ln << 2);
        float* lptr = &ring[slot][r][w << 8];    // wave-uniform base; HW adds lane*16
        __builtin_amdgcn_global_load_lds(
            (const __attribute__((address_space(1))) void*)gsrc,
            (__attribute__((address_space(3))) void*)lptr,
            16, 0, 0);
    };

    // horizontal max-9 for this thread's 4 cols from a staged LDS row
    auto hrow = [&](const float* row) -> float4 {
        const float4 v1 = *reinterpret_cast<const float4*>(&row[x4]);
        const float4 v0 = (tid == 0)   ? NEG4
                        : *reinterpret_cast<const float4*>(&row[x4 - 4]);
        const float4 v2 = (tid == 255) ? NEG4
                        : *reinterpret_cast<const float4*>(&row[x4 + 4]);
        return hmax9(v0, v1, v2);
    };

    // ---- prologue: stage halo rows -> slot0, chunk0 rows -> slot1 -----------
    #pragma unroll
    for (int j = 0; j < 8; ++j) {                // rows y0-4 .. y0+3 (clamp low)
        const int iy = y0 - 4 + j;
        stage(0, j, iy >= 0 ? iy : 0);
    }
    #pragma unroll
    for (int j = 0; j < 8; ++j) {                // rows y0+4 .. y0+11 (clamp high)
        const int iy = y0 + 4 + j;
        stage(1, j, iy < IMG ? iy : IMG - 1);
    }
    asm volatile("s_waitcnt vmcnt(8)" ::: "memory");   // halo done; chunk0 in flight
    __builtin_amdgcn_s_barrier();

    float4 C[8];                                 // carried hmax rows
    #pragma unroll
    for (int j = 0; j < 8; ++j)
        C[j] = (y0 - 4 + j >= 0) ? hrow(ring[0][j]) : NEG4;

    // ---- 4 chunks; chunk c lives in slot (c+1)&1 ----------------------------
    #pragma unroll
    for (int c = 0; c < 4; ++c) {
        // this chunk's DMAs done (stores / next DMAs may stay outstanding)
        if (c == 0) asm volatile("s_waitcnt vmcnt(0)" ::: "memory");
        else        asm volatile("s_waitcnt vmcnt(8)" ::: "memory");
        __builtin_amdgcn_s_barrier();            // all waves: chunk c readable,
                                                 // chunk c-1 fully consumed
        if (c < 3) {                             // prefetch chunk c+1 into slot c&1;
            #pragma unroll                       // stays in flight through consume
            for (int j = 0; j < 8; ++j) {
                const int iy = y0 + 12 + (c << 3) + j;
                stage(c & 1, j, iy < IMG ? iy : IMG - 1);
            }
        }

        const int r0 = y0 + (c << 3);
        float4 S[8];                             // suffix scan over carry
        S[7] = C[7];
        #pragma unroll
        for (int j = 6; j >= 0; --j) S[j] = max4(C[j], S[j + 1]);

        float4 P;
        #pragma unroll
        for (int t = 0; t < 8; ++t) {
            const float4 H = (r0 + 4 + t < IMG) ? hrow(ring[(c + 1) & 1][t]) : NEG4;
            P = (t == 0) ? H : max4(P, H);
            *reinterpret_cast<float4*>(oimg + (size_t)(r0 + t) * IMG + x4) = max4(S[t], P);
            C[t] = H;
        }
    }
}

extern "C" void kernel_launch(void* const* d_in, const int* in_sizes, int n_in,
                              void* d_out, int out_size, void* d_ws, size_t ws_size,
                              hipStream_t stream) {
    const float* in  = (const float*)d_in[0];
    float*       out = (float*)d_out;
    const int B = in_sizes[0] / (IMG * IMG);   // 16
    dim3 grid(IMG / ROWS, B);                  // 32 x 16 = 512 blocks
    dilate9x9<<<grid, 256, 0, stream>>>(in, out);
}

// Round 13
// 29.022 us; speedup vs baseline: 1.0631x; 1.0631x over previous
//
#include <hip/hip_runtime.h>
#include <math.h>

#define IMG  1024
#define ROWS 32     // 32 x 16 = 512 blocks -> 2 resident blocks/CU

#define NEG4 make_float4(-INFINITY, -INFINITY, -INFINITY, -INFINITY)

__device__ __forceinline__ float4 max4(const float4 a, const float4 b) {
    return make_float4(fmaxf(a.x, b.x), fmaxf(a.y, b.y),
                       fmaxf(a.z, b.z), fmaxf(a.w, b.w));
}

__global__ __launch_bounds__(256, 1)
void dilate9x9(const float* __restrict__ in, float* __restrict__ out) {
    const int tid  = threadIdx.x;
    const int lane = tid & 63;
    const int x4   = tid << 2;                // thread's 4 output cols
    const int y0   = blockIdx.x * ROWS;
    const int b    = blockIdx.y;

    const float* img  = in  + (size_t)b * IMG * IMG;
    float*       oimg = out + (size_t)b * IMG * IMG;

    const bool eL = (lane == 0)  && (x4 > 0);
    const bool eR = (lane == 63) && (x4 < IMG - 4);
    const int  xe = eL ? (x4 - 4) : (x4 + 4);

    // load one row (clamped): own float4 + edge float4 for wave-boundary lanes
    auto ldrow = [&](const int iy, float4& V, float4& E) {
        const int cy = iy < 0 ? 0 : (iy >= IMG ? IMG - 1 : iy);
        const size_t ro = (size_t)cy * IMG;
        V = *reinterpret_cast<const float4*>(img + ro + x4);
        E = NEG4;
        if (eL | eR) E = *reinterpret_cast<const float4*>(img + ro + xe);
    };

    // horizontal sliding max-9 from ONE aligned load per lane (R7-verified)
    auto hmax_row = [&](const float4 v, const float4 e) -> float4 {
        const float pre1 = fmaxf(v.x, v.y);
        const float pre2 = fmaxf(pre1, v.z);
        const float pre3 = fmaxf(pre2, v.w);
        const float suf2 = fmaxf(v.z, v.w);
        const float suf1 = fmaxf(v.y, suf2);
        const float suf0 = fmaxf(v.x, suf1);
        float ps0 = __shfl_up(suf0, 1, 64);
        float ps1 = __shfl_up(suf1, 1, 64);
        float ps2 = __shfl_up(suf2, 1, 64);
        float ps3 = __shfl_up(v.w , 1, 64);
        float np0 = __shfl_down(v.x , 1, 64);
        float np1 = __shfl_down(pre1, 1, 64);
        float np2 = __shfl_down(pre2, 1, 64);
        float np3 = __shfl_down(pre3, 1, 64);
        if (lane == 0) {
            ps3 = e.w;
            ps2 = fmaxf(e.z, e.w);
            ps1 = fmaxf(e.y, ps2);
            ps0 = fmaxf(e.x, ps1);
        }
        if (lane == 63) {
            np0 = e.x;
            np1 = fmaxf(e.x, e.y);
            np2 = fmaxf(np1, e.z);
            np3 = fmaxf(np2, e.w);
        }
        float4 r;
        r.x = fmaxf(fmaxf(ps0, suf0), np0);
        r.y = fmaxf(fmaxf(ps1, suf0), np1);
        r.z = fmaxf(fmaxf(ps2, suf0), np2);
        r.w = fmaxf(fmaxf(ps3, suf0), np3);
        return r;
    };

    // H-ring: 9 slots == window size; output row r = max over ALL slots.
    float4 H[9];
    // V-ring: depth-4 in-flight raw rows (load issued 4 iterations ahead of use)
    float4 Vr[4], Er[4];

    // ---- prologue: issue 12 row-loads as one clot ---------------------------
    float4 PV[8], PE[8];
    #pragma unroll
    for (int j = 0; j < 8; ++j) ldrow(y0 - 4 + j, PV[j], PE[j]);   // rows y0-4..y0+3
    #pragma unroll
    for (int d = 0; d < 4; ++d) ldrow(y0 + 4 + d, Vr[d], Er[d]);   // rows y0+4..y0+7
    __builtin_amdgcn_sched_barrier(0);

    #pragma unroll
    for (int j = 0; j < 8; ++j)
        H[j] = (y0 - 4 + j >= 0) ? hmax_row(PV[j], PE[j]) : NEG4;  // slots 0..7

    // ---- rolling main loop: uniform cadence (1 hmax, 1 load, 1 store / iter)
    #pragma unroll
    for (int r = 0; r < ROWS; ++r) {
        // fill slot (r+8)%9 with hmax of input row y0+r+4 (loaded 4 iters ago)
        const bool valid = (y0 + r + 4 < IMG);
        H[(r + 8) % 9] = valid ? hmax_row(Vr[r & 3], Er[r & 3]) : NEG4;

        // issue replacement load: input row y0+r+8 (used at iteration r+4)
        if (r < ROWS - 4) {
            ldrow(y0 + r + 8, Vr[r & 3], Er[r & 3]);
            __builtin_amdgcn_sched_barrier(0);   // keep the load issued HERE
        }

        // output row y0+r = max over the full ring (9 rows)
        float4 o = max4(H[0], H[1]);
        o = max4(o, H[2]);
        o = max4(o, H[3]);
        o = max4(o, H[4]);
        o = max4(o, H[5]);
        o = max4(o, H[6]);
        o = max4(o, H[7]);
        o = max4(o, H[8]);
        *reinterpret_cast<float4*>(oimg + (size_t)(y0 + r) * IMG + x4) = o;
    }
}

extern "C" void kernel_launch(void* const* d_in, const int* in_sizes, int n_in,
                              void* d_out, int out_size, void* d_ws, size_t ws_size,
                              hipStream_t stream) {
    const float* in  = (const float*)d_in[0];
    float*       out = (float*)d_out;
    const int B = in_sizes[0] / (IMG * IMG);   // 16
    dim3 grid(IMG / ROWS, B);                  // 32 x 16 = 512 blocks
    dilate9x9<<<grid, 256, 0, stream>>>(in, out);
}